// Round 1
// baseline (159.533 us; speedup 1.0000x reference)
//
#include <hip/hip_runtime.h>

namespace {

constexpr int Dh   = 64;
constexpr int Sseq = 2048;
constexpr int NT   = Sseq / 64;   // 32 q-tiles per head
constexpr int LDK  = 72;          // LDS row stride in bf16 elems (144 B, 16B-aligned, non-pow2)
constexpr float SCALE = 0.125f;   // 1/sqrt(64), exact in bf16 scaling

typedef __attribute__((ext_vector_type(8))) short frag8;   // 8 bf16 (4 VGPRs) MFMA operand
typedef __attribute__((ext_vector_type(4))) short short4v;
typedef __attribute__((ext_vector_type(4))) float f32x4;

__device__ __forceinline__ short f2bf(float f) {
    unsigned u = __builtin_bit_cast(unsigned, f);
    u += 0x7FFFu + ((u >> 16) & 1u);          // round-nearest-even to bf16
    return (short)(u >> 16);
}

__global__ __launch_bounds__(256) void battn_kernel(
    const float* __restrict__ qg, const float* __restrict__ kg,
    const float* __restrict__ vg, float* __restrict__ og)
{
    __shared__ short Klds[64 * LDK];       // K tile, row-major [key][d]
    __shared__ short VTlds[64 * LDK];      // V tile transposed [d][key]
    __shared__ short Plds[4][16 * LDK];    // per-wave P tile [qrow][key]

    // XCD-aware swizzle: each XCD (blockIdx%8 under round-robin dispatch) owns 4 heads.
    const int n   = blockIdx.x;
    const int xcd = n & 7;
    const int idx = n >> 3;                // 0..63
    const int bh  = xcd * 4 + (idx >> 4);  // 0..31
    const int qt0 = idx & 15;              // 0..15

    const size_t hoff = (size_t)bh * Sseq * Dh;
    const float* qh = qg + hoff;
    const float* kh = kg + hoff;
    const float* vh = vg + hoff;
    float*       oh = og + hoff;

    const int tid  = threadIdx.x;
    const int lane = tid & 63;
    const int w    = tid >> 6;   // wave 0..3, owns q-rows [w*16, w*16+16)
    const int g    = lane >> 4;  // 0..3
    const int c    = lane & 15;  // 0..15

    const int vd  = tid & 63;    // V^T staging: d column
    const int vkq = tid >> 6;    // V^T staging: key quarter

    for (int pass = 0; pass < 2; ++pass) {
        // pair tiles {qt0, 31-qt0}: every workgroup does exactly 33 KV blocks
        const int qt    = pass ? (NT - 1 - qt0) : qt0;
        const int qbase = qt * 64;

        // ---- load Q fragments (scaled, bf16) ----
        // A-frag layout: lane holds Q[qrow = w*16 + c][d = ks*32 + g*8 + j]
        frag8 qf[2];
        {
            const float* qr = qh + (size_t)(qbase + w * 16 + c) * Dh;
            #pragma unroll
            for (int ks = 0; ks < 2; ++ks) {
                const float4 x0 = *(const float4*)(qr + ks * 32 + g * 8);
                const float4 x1 = *(const float4*)(qr + ks * 32 + g * 8 + 4);
                qf[ks][0] = f2bf(x0.x * SCALE);
                qf[ks][1] = f2bf(x0.y * SCALE);
                qf[ks][2] = f2bf(x0.z * SCALE);
                qf[ks][3] = f2bf(x0.w * SCALE);
                qf[ks][4] = f2bf(x1.x * SCALE);
                qf[ks][5] = f2bf(x1.y * SCALE);
                qf[ks][6] = f2bf(x1.z * SCALE);
                qf[ks][7] = f2bf(x1.w * SCALE);
            }
        }

        float m_run[4], l_run[4];
        f32x4 oacc[4];
        #pragma unroll
        for (int r = 0; r < 4; ++r) { m_run[r] = -1e30f; l_run[r] = 0.f; }
        #pragma unroll
        for (int t = 0; t < 4; ++t) oacc[t] = f32x4{0.f, 0.f, 0.f, 0.f};

        // block-causal: kv block j visible iff j <= qt (no partial masks)
        for (int j = 0; j <= qt; ++j) {
            __syncthreads();   // protect K/V LDS from previous iteration's readers

            // ---- stage K tile (64x64 fp32 -> bf16 rows) ----
            {
                const float4* src = (const float4*)(kh + (size_t)j * 64 * Dh);
                #pragma unroll
                for (int p = 0; p < 4; ++p) {
                    const int   fe = (tid + p * 256) * 4;  // flat element index
                    const float4 x = src[tid + p * 256];
                    short4v y;
                    y[0] = f2bf(x.x); y[1] = f2bf(x.y);
                    y[2] = f2bf(x.z); y[3] = f2bf(x.w);
                    *(short4v*)&Klds[(fe >> 6) * LDK + (fe & 63)] = y;
                }
            }
            // ---- stage V^T tile (coalesced col reads -> d-major rows) ----
            {
                const float* src = vh + (size_t)(j * 64 + vkq * 16) * Dh + vd;
                frag8 y0, y1;
                #pragma unroll
                for (int jj = 0; jj < 8; ++jj) y0[jj] = f2bf(src[jj * Dh]);
                #pragma unroll
                for (int jj = 0; jj < 8; ++jj) y1[jj] = f2bf(src[(jj + 8) * Dh]);
                *(frag8*)&VTlds[vd * LDK + vkq * 16]     = y0;
                *(frag8*)&VTlds[vd * LDK + vkq * 16 + 8] = y1;
            }
            __syncthreads();

            // ---- S = Q K^T : D[m=qrow][n=key], m=(g*4+r), n=(t*16+c) ----
            f32x4 sacc[4];
            #pragma unroll
            for (int t = 0; t < 4; ++t) {
                f32x4 acc = f32x4{0.f, 0.f, 0.f, 0.f};
                #pragma unroll
                for (int ks = 0; ks < 2; ++ks) {
                    // B-frag: lane holds K[key = t*16 + c][d = ks*32 + g*8 + j]
                    const frag8 kf = *(const frag8*)&Klds[(t * 16 + c) * LDK + ks * 32 + g * 8];
                    acc = __builtin_amdgcn_mfma_f32_16x16x32_bf16(qf[ks], kf, acc, 0, 0, 0);
                }
                sacc[t] = acc;
            }

            // ---- wave-parallel online softmax (row = g*4 + r) ----
            float mn[4], corr[4], rs[4];
            #pragma unroll
            for (int r = 0; r < 4; ++r) {
                float pm = fmaxf(fmaxf(sacc[0][r], sacc[1][r]),
                                 fmaxf(sacc[2][r], sacc[3][r]));
                pm = fmaxf(pm, __shfl_xor(pm, 1));
                pm = fmaxf(pm, __shfl_xor(pm, 2));
                pm = fmaxf(pm, __shfl_xor(pm, 4));
                pm = fmaxf(pm, __shfl_xor(pm, 8));
                mn[r]   = fmaxf(m_run[r], pm);
                corr[r] = __expf(m_run[r] - mn[r]);
                m_run[r] = mn[r];
                rs[r] = 0.f;
            }
            #pragma unroll
            for (int t = 0; t < 4; ++t) {
                #pragma unroll
                for (int r = 0; r < 4; ++r) {
                    const float p = __expf(sacc[t][r] - mn[r]);
                    rs[r] += p;
                    // transpose D-layout -> row-major P[qrow][key] (per-wave buffer)
                    Plds[w][(g * 4 + r) * LDK + t * 16 + c] = f2bf(p);
                }
            }
            #pragma unroll
            for (int r = 0; r < 4; ++r) {
                float s = rs[r];
                s += __shfl_xor(s, 1);
                s += __shfl_xor(s, 2);
                s += __shfl_xor(s, 4);
                s += __shfl_xor(s, 8);
                l_run[r] = l_run[r] * corr[r] + s;
                oacc[0][r] *= corr[r];
                oacc[1][r] *= corr[r];
                oacc[2][r] *= corr[r];
                oacc[3][r] *= corr[r];
            }

            // ---- O += P V  (A=P from per-wave LDS, B=V from V^T rows) ----
            #pragma unroll
            for (int ks = 0; ks < 2; ++ks) {
                const frag8 pf = *(const frag8*)&Plds[w][c * LDK + ks * 32 + g * 8];
                #pragma unroll
                for (int t = 0; t < 4; ++t) {
                    // B-frag: lane holds V[key = ks*32+g*8+j][d = t*16 + c]
                    const frag8 vf = *(const frag8*)&VTlds[(t * 16 + c) * LDK + ks * 32 + g * 8];
                    oacc[t] = __builtin_amdgcn_mfma_f32_16x16x32_bf16(pf, vf, oacc[t], 0, 0, 0);
                }
            }
        }

        // ---- epilogue: normalize and store ----
        #pragma unroll
        for (int r = 0; r < 4; ++r) {
            const float inv = 1.f / l_run[r];
            float* orow = oh + (size_t)(qbase + w * 16 + g * 4 + r) * Dh;
            #pragma unroll
            for (int t = 0; t < 4; ++t)
                orow[t * 16 + c] = oacc[t][r] * inv;
        }
    }
}

} // namespace

extern "C" void kernel_launch(void* const* d_in, const int* in_sizes, int n_in,
                              void* d_out, int out_size, void* d_ws, size_t ws_size,
                              hipStream_t stream) {
    const float* q = (const float*)d_in[0];
    const float* k = (const float*)d_in[1];
    const float* v = (const float*)d_in[2];
    float* out = (float*)d_out;
    dim3 grid(2 * 16 * (NT / 2));   // 512 workgroups: (b,h) x 16 tile-pairs
    dim3 block(256);
    battn_kernel<<<grid, block, 0, stream>>>(q, k, v, out);
}

// Round 2
// 135.237 us; speedup vs baseline: 1.1797x; 1.1797x over previous
//
#include <hip/hip_runtime.h>

namespace {

constexpr int Dh   = 64;
constexpr int Sseq = 2048;
constexpr int NT   = Sseq / 64;     // 32 q-tiles per head
constexpr float SCALE = 0.125f;     // 1/sqrt(64)
constexpr float DEFER_THR = 8.0f;   // T13 defer-max threshold

typedef __attribute__((ext_vector_type(8))) short frag8;      // 8 bf16 MFMA operand
typedef __attribute__((ext_vector_type(4))) float f32x4;      // MFMA accumulator
typedef __attribute__((ext_vector_type(4))) short short4v;
typedef __attribute__((ext_vector_type(4))) unsigned int u32x4;

__device__ __forceinline__ short f2bf(float f) {
    unsigned u = __builtin_bit_cast(unsigned, f);
    u += 0x7FFFu + ((u >> 16) & 1u);          // RNE to bf16
    return (short)(u >> 16);
}
__device__ __forceinline__ unsigned pack2(float lo, float hi) {
    return (unsigned)(unsigned short)f2bf(lo) | ((unsigned)(unsigned short)f2bf(hi) << 16);
}
// key k -> LDS row. Bit permute [k5][k4k3][k2][k1k0] -> [k5][k2][k4k3][k1k0].
// Chosen so QK-tile t reads natural LDS rows t*16+c and the S^T output lands
// with lane g holding keys {g*8..g*8+7}+32ks == exactly the PV A-frag layout.
__device__ __forceinline__ int kperm(int kk) {
    return (kk & 0x23) | ((kk & 4) << 2) | ((kk & 0x18) >> 1);
}

__global__ __launch_bounds__(256) void battn_kernel(
    const float* __restrict__ qg, const float* __restrict__ kg,
    const float* __restrict__ vg, float* __restrict__ og)
{
    // double-buffered K (pi-permuted rows) and V^T ([d][key]); 128B rows,
    // XOR-swizzled with (row&7)<<4 bytes -> conflict-free ds_read_b128.
    __shared__ short Klds[2][64 * 64];
    __shared__ short Vlds[2][64 * 64];

    const int n   = blockIdx.x;
    const int xcd = n & 7;                 // XCD swizzle: 4 heads per XCD
    const int idx = n >> 3;
    const int bh  = xcd * 4 + (idx >> 4);  // 0..31
    const int qt0 = idx & 15;
    const int qtA = qt0;                   // small tile
    const int qtB = NT - 1 - qt0;          // large tile; work = 33 blocks/WG, balanced
    const int nb  = qtB + 1;               // staged KV blocks

    const size_t hoff = (size_t)bh * Sseq * Dh;
    const float* qh = qg + hoff;
    const float* kh = kg + hoff;
    const float* vh = vg + hoff;
    float*       oh = og + hoff;

    const int tid  = threadIdx.x;
    const int lane = tid & 63;
    const int w    = tid >> 6;     // wave 0..3 owns q-rows [w*16, w*16+16) of BOTH tiles
    const int g    = lane >> 4;
    const int c    = lane & 15;    // this lane's q-row within the wave
    const int swzc = (c & 7) << 3; // read-side XOR swizzle (short units)

    const int vd   = tid & 63;     // V^T staging: d
    const int vkq  = tid >> 6;     // V^T staging: key quarter
    const int vswz = (vd & 7) << 3;

    // ---- Q fragments, both tiles (QK B-operand: lane holds Q[qrow=c][d=ks*32+g*8+j]) ----
    frag8 qfA[2], qfB[2];
    {
        const float* qrA = qh + (size_t)(qtA * 64 + w * 16 + c) * Dh;
        const float* qrB = qh + (size_t)(qtB * 64 + w * 16 + c) * Dh;
        #pragma unroll
        for (int ks = 0; ks < 2; ++ks) {
            const float4 a0 = *(const float4*)(qrA + ks * 32 + g * 8);
            const float4 a1 = *(const float4*)(qrA + ks * 32 + g * 8 + 4);
            const float4 b0 = *(const float4*)(qrB + ks * 32 + g * 8);
            const float4 b1 = *(const float4*)(qrB + ks * 32 + g * 8 + 4);
            qfA[ks][0] = f2bf(a0.x * SCALE); qfA[ks][1] = f2bf(a0.y * SCALE);
            qfA[ks][2] = f2bf(a0.z * SCALE); qfA[ks][3] = f2bf(a0.w * SCALE);
            qfA[ks][4] = f2bf(a1.x * SCALE); qfA[ks][5] = f2bf(a1.y * SCALE);
            qfA[ks][6] = f2bf(a1.z * SCALE); qfA[ks][7] = f2bf(a1.w * SCALE);
            qfB[ks][0] = f2bf(b0.x * SCALE); qfB[ks][1] = f2bf(b0.y * SCALE);
            qfB[ks][2] = f2bf(b0.z * SCALE); qfB[ks][3] = f2bf(b0.w * SCALE);
            qfB[ks][4] = f2bf(b1.x * SCALE); qfB[ks][5] = f2bf(b1.y * SCALE);
            qfB[ks][6] = f2bf(b1.z * SCALE); qfB[ks][7] = f2bf(b1.w * SCALE);
        }
    }

    // ---- staging registers (T14: issue early, write late) ----
    float4 kx[4];
    float  vx[16];

    auto issue_loads = [&](int blk) {
        const float4* ksrc = (const float4*)(kh + (size_t)blk * 64 * Dh);
        #pragma unroll
        for (int p = 0; p < 4; ++p) kx[p] = ksrc[tid + p * 256];
        const float* vsrc = vh + ((size_t)blk * 64 + vkq * 16) * Dh + vd;
        #pragma unroll
        for (int i = 0; i < 16; ++i) vx[i] = vsrc[i * Dh];
    };
    auto write_stage = [&](int buf) {
        #pragma unroll
        for (int p = 0; p < 4; ++p) {
            const int fe   = (tid + p * 256) * 4;      // flat element in 64x64 K tile
            const int key  = fe >> 6;
            const int srow = kperm(key);
            const int scol = (fe & 63) ^ ((srow & 7) << 3);
            short4v y;
            y[0] = f2bf(kx[p].x); y[1] = f2bf(kx[p].y);
            y[2] = f2bf(kx[p].z); y[3] = f2bf(kx[p].w);
            *(short4v*)&Klds[buf][srow * 64 + scol] = y;
        }
        frag8 y0, y1;
        #pragma unroll
        for (int i = 0; i < 8; ++i) { y0[i] = f2bf(vx[i]); y1[i] = f2bf(vx[8 + i]); }
        *(frag8*)&Vlds[buf][vd * 64 + ((vkq * 16) ^ vswz)]     = y0;
        *(frag8*)&Vlds[buf][vd * 64 + ((vkq * 16 + 8) ^ vswz)] = y1;
    };

    float mA = -1e30f, lA = 0.f, mB = -1e30f, lB = 0.f;
    f32x4 oA[4], oB[4];
    #pragma unroll
    for (int t = 0; t < 4; ++t) { oA[t] = f32x4{0,0,0,0}; oB[t] = f32x4{0,0,0,0}; }

    // One KV-block step for one q-tile. Swapped MFMA: S^T = K·Q^T, so lane (g,c)
    // owns q-row c with keys {g*8..g*8+7, 32+g*8..+7} across (t,r) — exp results
    // pack straight into the PV A-fragment (no cross-lane P movement).
    auto tile_step = [&](int buf, const frag8* qf, float& m_run, float& l_run, f32x4* oacc) {
        f32x4 s[4];
        #pragma unroll
        for (int t = 0; t < 4; ++t) {
            f32x4 acc = f32x4{0, 0, 0, 0};
            #pragma unroll
            for (int ks = 0; ks < 2; ++ks) {
                const frag8 kf = *(const frag8*)&Klds[buf][(t * 16 + c) * 64 + ((ks * 32 + g * 8) ^ swzc)];
                acc = __builtin_amdgcn_mfma_f32_16x16x32_bf16(kf, qf[ks], acc, 0, 0, 0);
            }
            s[t] = acc;
        }
        float pmax = s[0][0];
        #pragma unroll
        for (int t = 0; t < 4; ++t)
            #pragma unroll
            for (int r = 0; r < 4; ++r) pmax = fmaxf(pmax, s[t][r]);
        pmax = fmaxf(pmax, __shfl_xor(pmax, 16));
        pmax = fmaxf(pmax, __shfl_xor(pmax, 32));
        if (!__all(pmax <= m_run + DEFER_THR)) {     // T13: skip rescale when max barely grew
            const float mn   = fmaxf(m_run, pmax);
            const float corr = __expf(m_run - mn);
            m_run = mn;
            l_run *= corr;
            #pragma unroll
            for (int r = 0; r < 4; ++r) {
                const float cr = __shfl(corr, g * 4 + r);   // O rows are g*4+r, not c
                #pragma unroll
                for (int t = 0; t < 4; ++t) oacc[t][r] *= cr;
            }
        }
        float e[4][4];
        float rs = 0.f;
        #pragma unroll
        for (int t = 0; t < 4; ++t)
            #pragma unroll
            for (int r = 0; r < 4; ++r) { e[t][r] = __expf(s[t][r] - m_run); rs += e[t][r]; }
        rs += __shfl_xor(rs, 16);
        rs += __shfl_xor(rs, 32);
        l_run += rs;
        u32x4 paf[2];
        paf[0] = u32x4{pack2(e[0][0], e[0][1]), pack2(e[0][2], e[0][3]),
                       pack2(e[1][0], e[1][1]), pack2(e[1][2], e[1][3])};
        paf[1] = u32x4{pack2(e[2][0], e[2][1]), pack2(e[2][2], e[2][3]),
                       pack2(e[3][0], e[3][1]), pack2(e[3][2], e[3][3])};
        #pragma unroll
        for (int ks = 0; ks < 2; ++ks) {
            const frag8 pf = __builtin_bit_cast(frag8, paf[ks]);
            #pragma unroll
            for (int t = 0; t < 4; ++t) {
                const frag8 vf = *(const frag8*)&Vlds[buf][(t * 16 + c) * 64 + ((ks * 32 + g * 8) ^ swzc)];
                oacc[t] = __builtin_amdgcn_mfma_f32_16x16x32_bf16(pf, vf, oacc[t], 0, 0, 0);
            }
        }
    };

    // ---- prologue: stage block 0 ----
    issue_loads(0);
    write_stage(0);

    int cur = 0;
    for (int sb = 0; sb < nb; ++sb) {
        const bool haveNext = (sb + 1 < nb);
        __syncthreads();                 // buf[cur] ready; prev readers of buf[cur^1] done
        if (haveNext) issue_loads(sb + 1);   // in flight across the whole compute phase
        tile_step(cur, qfB, mB, lB, oB);
        if (sb <= qtA) tile_step(cur, qfA, mA, lA, oA);   // uniform branch
        if (haveNext) write_stage(cur ^ 1);
        cur ^= 1;
    }

    // ---- epilogue ----
    auto store_tile = [&](int qt, float l_run, const f32x4* oacc) {
        const float linv = 1.f / l_run;
        #pragma unroll
        for (int r = 0; r < 4; ++r) {
            const float lr = __shfl(linv, g * 4 + r);
            float* orow = oh + (size_t)(qt * 64 + w * 16 + g * 4 + r) * Dh;
            #pragma unroll
            for (int t = 0; t < 4; ++t) orow[t * 16 + c] = oacc[t][r] * lr;
        }
    };
    store_tile(qtB, lB, oB);
    store_tile(qtA, lA, oA);
}

} // namespace

extern "C" void kernel_launch(void* const* d_in, const int* in_sizes, int n_in,
                              void* d_out, int out_size, void* d_ws, size_t ws_size,
                              hipStream_t stream) {
    const float* q = (const float*)d_in[0];
    const float* k = (const float*)d_in[1];
    const float* v = (const float*)d_in[2];
    float* out = (float*)d_out;
    dim3 grid(2 * 16 * (NT / 2));   // 512 WGs: (b,h) x 16 complementary tile-pairs
    dim3 block(256);
    battn_kernel<<<grid, block, 0, stream>>>(q, k, v, out);
}